// Round 1
// baseline (63.560 us; speedup 1.0000x reference)
//
#include <hip/hip_runtime.h>

struct cplx { float x, y; };

__device__ __forceinline__ cplx cmul(cplx a, cplx b) {
    cplx r;
    r.x = fmaf(a.x, b.x, -(a.y * b.y));
    r.y = fmaf(a.x, b.y,  a.y * b.x);
    return r;
}

// u0*a0 + u1*a1 (complex)
__device__ __forceinline__ cplx cmadd2(cplx u0, cplx a0, cplx u1, cplx a1) {
    cplx r;
    r.x = fmaf(u0.x, a0.x, -(u0.y * a0.y)) + fmaf(u1.x, a1.x, -(u1.y * a1.y));
    r.y = fmaf(u0.x, a0.y,  u0.y * a0.x)  + fmaf(u1.x, a1.y,  u1.y * a1.x);
    return r;
}

__global__ __launch_bounds__(256) void quanv_kernel(const float* __restrict__ x,
                                                    const float* __restrict__ prm,
                                                    float* __restrict__ out,
                                                    int n) {
    int t = blockIdx.x * blockDim.x + threadIdx.x;
    if (t >= n) return;

    int b  = t / 196;          // image
    int pi = t - b * 196;      // patch index
    int r  = pi / 14;
    int c  = pi - r * 14;

    // x is (B,1,28,28); patch top-left at (2r, 2c)
    const float* xb = x + b * 784 + r * 56 + c * 2;
    float2 top = *(const float2*)(xb);
    float2 bot = *(const float2*)(xb + 28);
    float ang[4] = { top.x, top.y, bot.x, bot.y };

    // RY encoding on |0000>: real product state.
    // wire w maps to bit (3-w) of the state index (wire 0 = MSB).
    float cw[4], sw[4];
#pragma unroll
    for (int w = 0; w < 4; ++w) __sincosf(0.5f * ang[w], &sw[w], &cw[w]);

    cplx st[16];
#pragma unroll
    for (int i = 0; i < 16; ++i) {
        float a = ((i & 8) ? sw[0] : cw[0]) * ((i & 4) ? sw[1] : cw[1])
                * ((i & 2) ? sw[2] : cw[2]) * ((i & 1) ? sw[3] : cw[3]);
        st[i].x = a; st[i].y = 0.0f;
    }

#pragma unroll
    for (int l = 0; l < 2; ++l) {
        // fused U = RZ(t2) * RY(t1) * RX(t0) per wire
#pragma unroll
        for (int w = 0; w < 4; ++w) {
            float sa, ca, sb, cb, sc, cc;
            __sincosf(0.5f * prm[(l * 4 + w) * 3 + 0], &sa, &ca);
            __sincosf(0.5f * prm[(l * 4 + w) * 3 + 1], &sb, &cb);
            __sincosf(0.5f * prm[(l * 4 + w) * 3 + 2], &sc, &cc);
            // M = RY*RX
            cplx m00 = {  cb * ca,  sb * sa };
            cplx m01 = { -sb * ca, -cb * sa };
            cplx m10 = {  sb * ca, -cb * sa };
            cplx m11 = {  cb * ca, -sb * sa };
            cplx em = { cc, -sc }, ep = { cc, sc };   // e^{-ic/2}, e^{+ic/2}
            cplx u00 = cmul(em, m00), u01 = cmul(em, m01);
            cplx u10 = cmul(ep, m10), u11 = cmul(ep, m11);

            int strd = 8 >> w;
#pragma unroll
            for (int i = 0; i < 16; ++i) {
                if (i & strd) continue;
                cplx a0 = st[i], a1 = st[i + strd];
                st[i]        = cmadd2(u00, a0, u01, a1);
                st[i + strd] = cmadd2(u10, a0, u11, a1);
            }
        }
        // CNOT ring: (0,1),(1,2),(2,3),(3,0) — pure register swaps
#pragma unroll
        for (int w = 0; w < 4; ++w) {
            int ctrl = w, tgt = (w + 1) & 3;
            int scm = 8 >> ctrl, stm = 8 >> tgt;
#pragma unroll
            for (int i = 0; i < 16; ++i) {
                if ((i & scm) && !(i & stm)) {
                    cplx tmp = st[i]; st[i] = st[i | stm]; st[i | stm] = tmp;
                }
            }
        }
    }

    // <Z_w> = sum_i |amp_i|^2 * (1 - 2*bit_{3-w}(i))
    float ev0 = 0.f, ev1 = 0.f, ev2 = 0.f, ev3 = 0.f;
#pragma unroll
    for (int i = 0; i < 16; ++i) {
        float p2 = fmaf(st[i].x, st[i].x, st[i].y * st[i].y);
        ev0 += (i & 8) ? -p2 : p2;
        ev1 += (i & 4) ? -p2 : p2;
        ev2 += (i & 2) ? -p2 : p2;
        ev3 += (i & 1) ? -p2 : p2;
    }
    float4 o = { ev0, ev1, ev2, ev3 };
    *(float4*)(out + t * 4) = o;
}

extern "C" void kernel_launch(void* const* d_in, const int* in_sizes, int n_in,
                              void* d_out, int out_size, void* d_ws, size_t ws_size,
                              hipStream_t stream) {
    const float* x   = (const float*)d_in[0];
    const float* prm = (const float*)d_in[1];
    float* out = (float*)d_out;

    int B = in_sizes[0] / 784;   // (B,1,28,28)
    int n = B * 196;             // patches total
    int block = 256;
    int grid = (n + block - 1) / block;
    quanv_kernel<<<grid, block, 0, stream>>>(x, prm, out, n);
}

// Round 2
// 62.129 us; speedup vs baseline: 1.0230x; 1.0230x over previous
//
#include <hip/hip_runtime.h>

struct cplx { float x, y; };

__device__ __forceinline__ cplx cmul(cplx a, cplx b) {
    cplx r;
    r.x = fmaf(a.x, b.x, -(a.y * b.y));
    r.y = fmaf(a.x, b.y,  a.y * b.x);
    return r;
}

// u0*a0 + u1*a1 (complex)
__device__ __forceinline__ cplx cmadd2(cplx u0, cplx a0, cplx u1, cplx a1) {
    cplx r;
    r.x = fmaf(u0.x, a0.x, -(u0.y * a0.y)) + fmaf(u1.x, a1.x, -(u1.y * a1.y));
    r.y = fmaf(u0.x, a0.y,  u0.y * a0.x)  + fmaf(u1.x, a1.y,  u1.y * a1.x);
    return r;
}

// Precompute the 8 uniform fused gates U = RZ*RY*RX, one per (layer,wire).
// Layout: g[k*8 + {u00x,u00y, u01x,u01y, u10x,u10y, u11x,u11y}], k = l*4+w.
__global__ void prep_gates(const float* __restrict__ prm, float* __restrict__ g) {
    int k = threadIdx.x;
    if (k >= 8) return;
    float sa, ca, sb, cb, sc, cc;
    __sincosf(0.5f * prm[k * 3 + 0], &sa, &ca);
    __sincosf(0.5f * prm[k * 3 + 1], &sb, &cb);
    __sincosf(0.5f * prm[k * 3 + 2], &sc, &cc);
    // M = RY*RX
    cplx m00 = {  cb * ca,  sb * sa };
    cplx m01 = { -sb * ca, -cb * sa };
    cplx m10 = {  sb * ca, -cb * sa };
    cplx m11 = {  cb * ca, -sb * sa };
    cplx em = { cc, -sc }, ep = { cc, sc };   // e^{-ic/2}, e^{+ic/2}
    cplx u00 = cmul(em, m00), u01 = cmul(em, m01);
    cplx u10 = cmul(ep, m10), u11 = cmul(ep, m11);
    float* o = g + k * 8;
    o[0] = u00.x; o[1] = u00.y; o[2] = u01.x; o[3] = u01.y;
    o[4] = u10.x; o[5] = u10.y; o[6] = u11.x; o[7] = u11.y;
}

__global__ __launch_bounds__(256) void quanv_kernel(const float* __restrict__ x,
                                                    const float* __restrict__ g,
                                                    float* __restrict__ out,
                                                    int n) {
    int t = blockIdx.x * blockDim.x + threadIdx.x;
    if (t >= n) return;

    int b  = t / 196;          // image
    int pi = t - b * 196;      // patch index
    int r  = pi / 14;
    int c  = pi - r * 14;

    // x is (B,1,28,28); patch top-left at (2r, 2c)
    const float* xb = x + b * 784 + r * 56 + c * 2;
    float2 top = *(const float2*)(xb);
    float2 bot = *(const float2*)(xb + 28);
    float ang[4] = { top.x, top.y, bot.x, bot.y };

    // Uniform gate matrices (wave-uniform address -> scalar loads)
    cplx U[8][4];
#pragma unroll
    for (int k = 0; k < 8; ++k) {
        const float* o = g + k * 8;
        U[k][0] = { o[0], o[1] };
        U[k][1] = { o[2], o[3] };
        U[k][2] = { o[4], o[5] };
        U[k][3] = { o[6], o[7] };
    }

    // Encoding RY(ang) on |0> fused with layer-0 single-qubit gates:
    // per-wire state vector v_w = U_w * (c_w, s_w)^T  (still a product state,
    // since layer-0 CNOTs come after all layer-0 single-qubit gates).
    cplx v[4][2];
#pragma unroll
    for (int w = 0; w < 4; ++w) {
        float cw, sw;
        __sincosf(0.5f * ang[w], &sw, &cw);
        v[w][0].x = fmaf(cw, U[w][0].x, sw * U[w][1].x);
        v[w][0].y = fmaf(cw, U[w][0].y, sw * U[w][1].y);
        v[w][1].x = fmaf(cw, U[w][2].x, sw * U[w][3].x);
        v[w][1].y = fmaf(cw, U[w][2].y, sw * U[w][3].y);
    }

    // Build 16-amp product state. wire w -> bit (3-w) of state index.
    cplx p01[4], p23[4], st[16];
#pragma unroll
    for (int j = 0; j < 4; ++j) {
        p01[j] = cmul(v[0][j >> 1], v[1][j & 1]);
        p23[j] = cmul(v[2][j >> 1], v[3][j & 1]);
    }
#pragma unroll
    for (int i = 0; i < 16; ++i) st[i] = cmul(p01[i >> 2], p23[i & 3]);

    // Layer-0 CNOT ring: (0,1),(1,2),(2,3),(3,0) — compile-time register swaps
#pragma unroll
    for (int w = 0; w < 4; ++w) {
        int scm = 8 >> w, stm = 8 >> ((w + 1) & 3);
#pragma unroll
        for (int i = 0; i < 16; ++i) {
            if ((i & scm) && !(i & stm)) {
                cplx tmp = st[i]; st[i] = st[i | stm]; st[i | stm] = tmp;
            }
        }
    }

    // Layer-1 single-qubit gates (U[4..7])
#pragma unroll
    for (int w = 0; w < 4; ++w) {
        cplx u00 = U[4 + w][0], u01 = U[4 + w][1];
        cplx u10 = U[4 + w][2], u11 = U[4 + w][3];
        int strd = 8 >> w;
#pragma unroll
        for (int i = 0; i < 16; ++i) {
            if (i & strd) continue;
            cplx a0 = st[i], a1 = st[i + strd];
            st[i]        = cmadd2(u00, a0, u01, a1);
            st[i + strd] = cmadd2(u10, a0, u11, a1);
        }
    }

    // Layer-1 CNOT ring
#pragma unroll
    for (int w = 0; w < 4; ++w) {
        int scm = 8 >> w, stm = 8 >> ((w + 1) & 3);
#pragma unroll
        for (int i = 0; i < 16; ++i) {
            if ((i & scm) && !(i & stm)) {
                cplx tmp = st[i]; st[i] = st[i | stm]; st[i | stm] = tmp;
            }
        }
    }

    // probs + signed butterfly: ev_w = sum_i (1-2*bit_{3-w}(i)) |st_i|^2
    float p[16];
#pragma unroll
    for (int i = 0; i < 16; ++i) p[i] = fmaf(st[i].x, st[i].x, st[i].y * st[i].y);

    float a[8], ev3 = 0.f;
#pragma unroll
    for (int i = 0; i < 8; ++i) { a[i] = p[2*i] + p[2*i+1]; ev3 += p[2*i] - p[2*i+1]; }
    float bs[4], ev2 = 0.f;
#pragma unroll
    for (int i = 0; i < 4; ++i) { bs[i] = a[2*i] + a[2*i+1]; ev2 += a[2*i] - a[2*i+1]; }
    float ev1 = (bs[0] - bs[1]) + (bs[2] - bs[3]);
    float ev0 = (bs[0] + bs[1]) - (bs[2] + bs[3]);

    float4 o4 = { ev0, ev1, ev2, ev3 };
    *(float4*)(out + t * 4) = o4;
}

extern "C" void kernel_launch(void* const* d_in, const int* in_sizes, int n_in,
                              void* d_out, int out_size, void* d_ws, size_t ws_size,
                              hipStream_t stream) {
    const float* x   = (const float*)d_in[0];
    const float* prm = (const float*)d_in[1];
    float* out = (float*)d_out;
    float* gates = (float*)d_ws;   // 64 floats

    int B = in_sizes[0] / 784;   // (B,1,28,28)
    int n = B * 196;             // patches total

    prep_gates<<<1, 64, 0, stream>>>(prm, gates);
    int block = 256;
    int grid = (n + block - 1) / block;
    quanv_kernel<<<grid, block, 0, stream>>>(x, gates, out, n);
}

// Round 3
// 60.146 us; speedup vs baseline: 1.0568x; 1.0330x over previous
//
#include <hip/hip_runtime.h>

struct cplx { float x, y; };

__device__ __forceinline__ cplx cmul(cplx a, cplx b) {
    cplx r;
    r.x = fmaf(a.x, b.x, -(a.y * b.y));
    r.y = fmaf(a.x, b.y,  a.y * b.x);
    return r;
}

// u0*a0 + u1*a1 (complex)
__device__ __forceinline__ cplx cmadd2(cplx u0, cplx a0, cplx u1, cplx a1) {
    cplx r;
    r.x = fmaf(u0.x, a0.x, -(u0.y * a0.y)) + fmaf(u1.x, a1.x, -(u1.y * a1.y));
    r.y = fmaf(u0.x, a0.y,  u0.y * a0.x)  + fmaf(u1.x, a1.y,  u1.y * a1.x);
    return r;
}

__global__ __launch_bounds__(256) void quanv_kernel(const float* __restrict__ x,
                                                    const float* __restrict__ prm,
                                                    float* __restrict__ out,
                                                    int n) {
    // Per-block: compute the 8 uniform fused gates U = RZ*RY*RX into LDS.
    __shared__ float gs[64];
    int tid = threadIdx.x;
    if (tid < 8) {
        float sa, ca, sb, cb, sc, cc;
        __sincosf(0.5f * prm[tid * 3 + 0], &sa, &ca);
        __sincosf(0.5f * prm[tid * 3 + 1], &sb, &cb);
        __sincosf(0.5f * prm[tid * 3 + 2], &sc, &cc);
        cplx m00 = {  cb * ca,  sb * sa };   // RY*RX
        cplx m01 = { -sb * ca, -cb * sa };
        cplx m10 = {  sb * ca, -cb * sa };
        cplx m11 = {  cb * ca, -sb * sa };
        cplx em = { cc, -sc }, ep = { cc, sc };
        cplx u00 = cmul(em, m00), u01 = cmul(em, m01);
        cplx u10 = cmul(ep, m10), u11 = cmul(ep, m11);
        float* o = gs + tid * 8;
        o[0] = u00.x; o[1] = u00.y; o[2] = u01.x; o[3] = u01.y;
        o[4] = u10.x; o[5] = u10.y; o[6] = u11.x; o[7] = u11.y;
    }
    __syncthreads();

    int t = blockIdx.x * 256 + tid;
    if (t >= n) return;

    int b  = t / 196;
    int pi = t - b * 196;
    int r  = pi / 14;
    int c  = pi - r * 14;

    const float* xb = x + b * 784 + r * 56 + c * 2;
    float2 top = *(const float2*)(xb);
    float2 bot = *(const float2*)(xb + 28);
    float ang[4] = { top.x, top.y, bot.x, bot.y };

    // Encoding RY fused with layer-0 single-qubit gate: v_w = U_w * (c,s)^T
    cplx v[4][2];
#pragma unroll
    for (int w = 0; w < 4; ++w) {
        float cw, sw;
        __sincosf(0.5f * ang[w], &sw, &cw);
        const float* o = gs + w * 8;            // LDS broadcast reads
        v[w][0].x = fmaf(cw, o[0], sw * o[2]);
        v[w][0].y = fmaf(cw, o[1], sw * o[3]);
        v[w][1].x = fmaf(cw, o[4], sw * o[6]);
        v[w][1].y = fmaf(cw, o[5], sw * o[7]);
    }

    // Product state with layer-0 CNOT ring fused as a compile-time permutation.
    // wire w <-> state bit (3-w).  CNOTs (0,1)(1,2)(2,3)(3,0) in sequence:
    // n1=w1^w0, n2=w2^w1^w0, n3=w3^w2^w1^w0, n0=w3^w2^w1.
    cplx p01[4], p23[4], st[16];
#pragma unroll
    for (int j = 0; j < 4; ++j) {
        p01[j] = cmul(v[0][j >> 1], v[1][j & 1]);
        p23[j] = cmul(v[2][j >> 1], v[3][j & 1]);
    }
#pragma unroll
    for (int j = 0; j < 16; ++j) {
        int w0 = (j >> 3) & 1, w1 = (j >> 2) & 1, w2 = (j >> 1) & 1, w3 = j & 1;
        int n1 = w1 ^ w0;
        int n2 = w2 ^ w1 ^ w0;
        int n3 = w3 ^ w2 ^ w1 ^ w0;
        int n0 = w3 ^ w2 ^ w1;
        int pj = (n0 << 3) | (n1 << 2) | (n2 << 1) | n3;   // compile-time
        st[pj] = cmul(p01[j >> 2], p23[j & 3]);
    }

    // Layer-1 single-qubit gates (gates 4..7 from LDS)
#pragma unroll
    for (int w = 0; w < 4; ++w) {
        const float* o = gs + (4 + w) * 8;
        cplx u00 = { o[0], o[1] }, u01 = { o[2], o[3] };
        cplx u10 = { o[4], o[5] }, u11 = { o[6], o[7] };
        int strd = 8 >> w;
#pragma unroll
        for (int i = 0; i < 16; ++i) {
            if (i & strd) continue;
            cplx a0 = st[i], a1 = st[i + strd];
            st[i]        = cmadd2(u00, a0, u01, a1);
            st[i + strd] = cmadd2(u10, a0, u11, a1);
        }
    }

    // Final CNOT ring folded into observables (Clifford pushthrough):
    // <Z0>f = <Z1Z2Z3>, <Z1>f = <Z0Z1>, <Z2>f = <Z0Z1Z2>, <Z3>f = <Z0Z1Z2Z3>
    // State-bit parity masks: ev0:7, ev1:12, ev2:14, ev3:15.
    float p[16];
#pragma unroll
    for (int i = 0; i < 16; ++i) p[i] = fmaf(st[i].x, st[i].x, st[i].y * st[i].y);

    float as[8], ad[8];
#pragma unroll
    for (int i = 0; i < 8; ++i) { as[i] = p[2*i] + p[2*i+1]; ad[i] = p[2*i] - p[2*i+1]; }
    float bss[4], bsd[4], bdd[4];
#pragma unroll
    for (int i = 0; i < 4; ++i) {
        bss[i] = as[2*i] + as[2*i+1];
        bsd[i] = as[2*i] - as[2*i+1];
        bdd[i] = ad[2*i] - ad[2*i+1];
    }
    // k bits = (b3,b2)
    float ev1 = (bss[0] - bss[1]) - (bss[2] - bss[3]);   // mask 12: (-1)^(b3+b2)
    float ev2 = (bsd[0] - bsd[1]) - (bsd[2] - bsd[3]);   // mask 14
    float ev0 = (bdd[0] - bdd[1]) + (bdd[2] - bdd[3]);   // mask 7: (-1)^(b2)
    float ev3 = (bdd[0] - bdd[1]) - (bdd[2] - bdd[3]);   // mask 15

    float4 o4 = { ev0, ev1, ev2, ev3 };
    *(float4*)(out + t * 4) = o4;
}

extern "C" void kernel_launch(void* const* d_in, const int* in_sizes, int n_in,
                              void* d_out, int out_size, void* d_ws, size_t ws_size,
                              hipStream_t stream) {
    const float* x   = (const float*)d_in[0];
    const float* prm = (const float*)d_in[1];
    float* out = (float*)d_out;

    int B = in_sizes[0] / 784;   // (B,1,28,28)
    int n = B * 196;             // patches total
    int block = 256;
    int grid = (n + block - 1) / block;
    quanv_kernel<<<grid, block, 0, stream>>>(x, prm, out, n);
}